// Round 13
// baseline (129.717 us; speedup 1.0000x reference)
//
#include <hip/hip_runtime.h>

// Problem dims (hard-coded in reference)
#define DD   768
#define NN   512
#define MM   512

#define PRE_K 2.88539008177792681472f   // 2*log2(e)

typedef _Float16 h8 __attribute__((ext_vector_type(8)));  // 8 f16 (4 VGPRs)
typedef __attribute__((ext_vector_type(4))) float f32x4;  // MFMA C/D
typedef __attribute__((ext_vector_type(2))) float f32x2;  // packed fp32 (v_pk_*)

__device__ __forceinline__ float fexp(float x) { return __builtin_amdgcn_exp2f(x); }
__device__ __forceinline__ float frcp(float x) { return __builtin_amdgcn_rcpf(x); }
// tanh(x) = 1 - 2/(1 + e^{2x}); saturates correctly via exp2->inf/0 + rcp.
__device__ __forceinline__ float fast_tanh(float x) {
  return 1.0f - 2.0f * frcp(fexp(PRE_K * x) + 1.0f);
}
// Ledger: R13 keep HW trans. R17 mega-kernel catastrophic. R18 bounds(256,8)
// spills. R19(R6, 131.1): main 44.8 @ occ 40. R20 BK64 neutral. R21 in-GEMM
// convert neutral. R22(R9): harness fill = 42us fixed; gap ~3-4us/dispatch.
// R23/R24: Q-fusion flat. R25(R12, BEST 127.5): packed f32 pk-math, main 43.2.
// Model: main ~= trans-pipe (20.5us) + LDS-issue (~20us) SERIALIZED. R26(this):
// cut LDS issues/element-output 2.7x — b128 loads (not 8x b64) + 16x64 tile
// (4 outputs/thread amortize tv/w2v broadcasts). Trans floor unchanged.

// fp32 -> f16 hi/lo split (pair covers ~21 mantissa bits)
__device__ __forceinline__ void splitf(float x, ushort& h, ushort& l) {
  const _Float16 hh = (_Float16)x;
  const _Float16 ll = (_Float16)(x - (float)hh);
  h = __builtin_bit_cast(unsigned short, hh);
  l = __builtin_bit_cast(unsigned short, ll);
}

// ---- fused prep (R0 verbatim) ----------------------------------------------
// blocks [0,1344): elementwise f16 hi/lo split of text/visual/W3
// blocks [1344,2496): transpose+split W1/W2 -> [j][k]
// blocks [2496,2752): T-init — out[n,m] = T[n] = sum_d text[n,d]
__global__ __launch_bounds__(256) void prep_kernel(
    const float* __restrict__ text, const float* __restrict__ visual,
    const float* __restrict__ W1, const float* __restrict__ W2,
    const float* __restrict__ W3,
    ushort* __restrict__ th, ushort* __restrict__ tl,
    ushort* __restrict__ vh, ushort* __restrict__ vl,
    ushort* __restrict__ w3h, ushort* __restrict__ w3l,
    ushort* __restrict__ w1th, ushort* __restrict__ w1tl,
    ushort* __restrict__ w2th, ushort* __restrict__ w2tl,
    float* __restrict__ out)
{
  __shared__ float Lt[32][33];
  const int b = blockIdx.x;
  const int t = threadIdx.x;

  if (b < 1344) {
    const float* src; ushort *dh, *dl; size_t off;
    if (b < 384)      { src = text;   dh = th;  dl = tl;  off = (size_t)b * 1024; }
    else if (b < 768) { src = visual; dh = vh;  dl = vl;  off = (size_t)(b - 384) * 1024; }
    else              { src = W3;     dh = w3h; dl = w3l; off = (size_t)(b - 768) * 1024; }
    const size_t i = off + (size_t)t * 4;
    const float4 v = *(const float4*)&src[i];
    ushort4 h, l;
    splitf(v.x, h.x, l.x); splitf(v.y, h.y, l.y);
    splitf(v.z, h.z, l.z); splitf(v.w, h.w, l.w);
    *(ushort4*)&dh[i] = h;
    *(ushort4*)&dl[i] = l;
  } else if (b < 2496) {
    const int tt = b - 1344;
    const bool second = tt >= 576;
    const int tile = second ? tt - 576 : tt;
    const float* W = second ? W2 : W1;
    ushort* oh = second ? w2th : w1th;
    ushort* ol = second ? w2tl : w1tl;
    const int k0 = (tile / 24) * 32, j0 = (tile % 24) * 32;
    {
      const int k = t >> 3, j4 = (t & 7) * 4;
      const float4 v = *(const float4*)&W[(size_t)(k0 + k) * DD + j0 + j4];
      Lt[j4 + 0][k] = v.x; Lt[j4 + 1][k] = v.y;
      Lt[j4 + 2][k] = v.z; Lt[j4 + 3][k] = v.w;
    }
    __syncthreads();
    {
      const int j = t >> 3, k4 = (t & 7) * 4;
      ushort4 h, l;
      splitf(Lt[j][k4 + 0], h.x, l.x); splitf(Lt[j][k4 + 1], h.y, l.y);
      splitf(Lt[j][k4 + 2], h.z, l.z); splitf(Lt[j][k4 + 3], h.w, l.w);
      *(ushort4*)&oh[(size_t)(j0 + j) * DD + k0 + k4] = h;
      *(ushort4*)&ol[(size_t)(j0 + j) * DD + k0 + k4] = l;
    }
  } else {
    // T-init: rows n0, n0+1; out[row][:] = T[row]
    float* red = (float*)Lt;          // 258 floats needed, 1056 available
    const int u = b - 2496;
    const int n0 = u * 2;
    const int half = t >> 7;
    const int lt = t & 127;

    const float* tr = text + (size_t)(n0 + half) * DD;
    float s = 0.f;
    #pragma unroll
    for (int i = 0; i < DD / 128; ++i) s += tr[lt + i * 128];
    red[t] = s;
    __syncthreads();
    #pragma unroll
    for (int st = 64; st > 0; st >>= 1) {
      if (lt < st) red[t] += red[t + st];
      __syncthreads();
    }
    const float Tn = red[half << 7];
    float4 o; o.x = Tn; o.y = Tn; o.z = Tn; o.w = Tn;
    *(float4*)&out[(size_t)(n0 + half) * MM + lt * 4] = o;
  }
}

// ---- staged-LDS MFMA GEMM core, 32x64 tile + k0 (R6-proven) ----------------
#define BK   32
#define LROW 40            // padded LDS row stride (f16): 2-way banks, 16B-aligned
#define APL  (32 * LROW)   // one A plane (rows x LROW), in ushorts
#define BPL  (64 * LROW)   // one B plane

template <bool ALO>
__device__ __forceinline__ void gemm_core32(
    ushort* __restrict__ As, ushort* __restrict__ Bs,  // [2 buf][2 hi/lo][plane]
    const ushort* __restrict__ Ahg, const ushort* __restrict__ Alg,
    const ushort* __restrict__ Bhg, const ushort* __restrict__ Blg,
    int i0, int j0, int k0, int nsteps, f32x4* acc)
{
  const int tid = threadIdx.x;
  const int row = tid >> 2;             // 0..63 staging row (B); 0..31 for A
  const int ks8 = (tid & 3) * 8;        // 0,8,16,24 (f16)
  const bool doA = (row < 32);          // waves 0,1 stage A too (wave-uniform)
  const size_t ga = (size_t)(i0 + row) * DD + k0 + ks8;
  const size_t gb = (size_t)(j0 + row) * DD + k0 + ks8;
  const int lw = row * LROW + ks8;

  const int lane = tid & 63, wave = tid >> 6;
  const int r15 = lane & 15, quad = lane >> 4;
  const int wr = wave >> 1, wc = wave & 1;              // 2x2 wave grid
  const int fa = (wr * 16 + r15) * LROW + quad * 8;     // A frag offset
  const int fb = (wc * 32 + r15) * LROW + quad * 8;     // B frag base

  h8 pah, pal, pbh, pbl;
  if (doA) {
    pah = *(const h8*)(Ahg + ga);
    if (ALO) pal = *(const h8*)(Alg + ga);
  }
  pbh = *(const h8*)(Bhg + gb);
  pbl = *(const h8*)(Blg + gb);

  int p = 0;
  if (doA) {
    *(h8*)&As[lw] = pah;
    if (ALO) *(h8*)&As[APL + lw] = pal;
  }
  *(h8*)&Bs[lw] = pbh;
  *(h8*)&Bs[BPL + lw] = pbl;
  __syncthreads();

  for (int s = 0; s < nsteps; ++s) {
    const bool more = (s + 1 < nsteps);
    if (more) {  // issue next chunk's globals; MFMA below hides latency
      if (doA) {
        pah = *(const h8*)(Ahg + ga + (s + 1) * BK);
        if (ALO) pal = *(const h8*)(Alg + ga + (s + 1) * BK);
      }
      pbh = *(const h8*)(Bhg + gb + (s + 1) * BK);
      pbl = *(const h8*)(Blg + gb + (s + 1) * BK);
    }
    ushort* Ac = As + p * 2 * APL;
    ushort* Bc = Bs + p * 2 * BPL;
    const h8 a_h = *(const h8*)&Ac[fa];
    h8 a_l; if (ALO) a_l = *(const h8*)&Ac[APL + fa];
    h8 b_h[2], b_l[2];
    #pragma unroll
    for (int c = 0; c < 2; ++c) {
      b_h[c] = *(const h8*)&Bc[fb + c * 16 * LROW];
      b_l[c] = *(const h8*)&Bc[BPL + fb + c * 16 * LROW];
    }
    #pragma unroll
    for (int c = 0; c < 2; ++c)
      acc[c] = __builtin_amdgcn_mfma_f32_16x16x32_f16(a_h, b_h[c], acc[c], 0, 0, 0);
    #pragma unroll
    for (int c = 0; c < 2; ++c)
      acc[c] = __builtin_amdgcn_mfma_f32_16x16x32_f16(a_h, b_l[c], acc[c], 0, 0, 0);
    if (ALO) {
      #pragma unroll
      for (int c = 0; c < 2; ++c)
        acc[c] = __builtin_amdgcn_mfma_f32_16x16x32_f16(a_l, b_h[c], acc[c], 0, 0, 0);
    }
    if (more) {
      const int q = p ^ 1;
      ushort* An = As + q * 2 * APL;
      ushort* Bn = Bs + q * 2 * BPL;
      if (doA) {
        *(h8*)&An[lw] = pah;
        if (ALO) *(h8*)&An[APL + lw] = pal;
      }
      *(h8*)&Bn[lw] = pbh;
      *(h8*)&Bn[BPL + lw] = pbl;
    }
    __syncthreads();
    p ^= 1;
  }
}

// z=0: A=text@W1 -> Ah/Al(f16)  z=1: kw2t=PRE_K*text@W2  z=2: kw3v=PRE_K*visual@W3^T
// grid (DD/64, NN/32, 3) = (12, 16, 3) = 576 blocks.
__global__ __launch_bounds__(256) void mfma1_kernel(
    const ushort* __restrict__ th, const ushort* __restrict__ tl,
    const ushort* __restrict__ vh, const ushort* __restrict__ vl,
    const ushort* __restrict__ w1th, const ushort* __restrict__ w1tl,
    const ushort* __restrict__ w2th, const ushort* __restrict__ w2tl,
    const ushort* __restrict__ w3h, const ushort* __restrict__ w3l,
    ushort* __restrict__ Ah, ushort* __restrict__ Al,
    float* __restrict__ kw2t, float* __restrict__ kw3v)
{
  __shared__ ushort As[2 * 2 * APL];   // 10240 B
  __shared__ ushort Bs[2 * 2 * BPL];   // 20480 B

  const int z  = blockIdx.z;
  const int j0 = blockIdx.x * 64;
  const int i0 = blockIdx.y * 32;

  f32x4 acc[2];
  acc[0] = (f32x4){0.f, 0.f, 0.f, 0.f};
  acc[1] = (f32x4){0.f, 0.f, 0.f, 0.f};

  if (z == 0)
    gemm_core32<true >(As, Bs, th, tl, w1th, w1tl, i0, j0, 0, DD / BK, acc);
  else if (z == 1)
    gemm_core32<false>(As, Bs, th, tl, w2th, w2tl, i0, j0, 0, DD / BK, acc);
  else
    gemm_core32<false>(As, Bs, vh, vl, w3h,  w3l,  i0, j0, 0, DD / BK, acc);

  const int lane = threadIdx.x & 63, wave = threadIdx.x >> 6;
  const int r15 = lane & 15, quad = lane >> 4;
  const int wr = wave >> 1, wc = wave & 1;
  // C/D layout: col=lane&15 (B row j), row=quad*4+reg (A row i)
  if (z == 0) {
    #pragma unroll
    for (int c = 0; c < 2; ++c)
      #pragma unroll
      for (int r = 0; r < 4; ++r) {
        const size_t o = (size_t)(i0 + wr * 16 + quad * 4 + r) * DD
                       + j0 + wc * 32 + c * 16 + r15;
        splitf(acc[c][r], Ah[o], Al[o]);
      }
  } else {
    float* Out = (z == 1) ? kw2t : kw3v;
    #pragma unroll
    for (int c = 0; c < 2; ++c)
      #pragma unroll
      for (int r = 0; r < 4; ++r)
        Out[(size_t)(i0 + wr * 16 + quad * 4 + r) * DD + j0 + wc * 32 + c * 16 + r15] =
            acc[c][r] * PRE_K;
  }
}

// Q[z] = A @ visual^T over K quarter z.  grid (8, 16, 4) = 512 blocks (2/CU).
__global__ __launch_bounds__(256) void mfma2_kernel(
    const ushort* __restrict__ Ah, const ushort* __restrict__ Al,
    const ushort* __restrict__ vh, const ushort* __restrict__ vl,
    float* __restrict__ Q)
{
  __shared__ ushort As[2 * 2 * APL];
  __shared__ ushort Bs[2 * 2 * BPL];

  const int z  = blockIdx.z;
  const int j0 = blockIdx.x * 64;
  const int i0 = blockIdx.y * 32;

  f32x4 acc[2];
  acc[0] = (f32x4){0.f, 0.f, 0.f, 0.f};
  acc[1] = (f32x4){0.f, 0.f, 0.f, 0.f};
  gemm_core32<true>(As, Bs, Ah, Al, vh, vl, i0, j0, z * (DD / 4), (DD / 4) / BK, acc);

  const int lane = threadIdx.x & 63, wave = threadIdx.x >> 6;
  const int r15 = lane & 15, quad = lane >> 4;
  const int wr = wave >> 1, wc = wave & 1;
  float* Qp = Q + (size_t)z * NN * MM;
  #pragma unroll
  for (int c = 0; c < 2; ++c)
    #pragma unroll
    for (int r = 0; r < 4; ++r)
      Qp[(size_t)(i0 + wr * 16 + quad * 4 + r) * MM + j0 + wc * 32 + c * 16 + r15] =
          acc[c][r];
}

// ---- main fused kernel (R26: 16x64 tile, 4 outputs/thread, b128 loads) -----
// Per j-group (4 cols x 4 outputs = 16 element-outputs): 6 ds_read_b128 +
// 24 v_pk + 32 trans. LDS issues/eo = 0.375 (R12 was 1.0). Trans floor 20.5us
// unchanged. LDS 27648 B -> 4 blocks/CU at grid (8,32,4) = 1024 blocks.
#define DCH    32
#define DRANGE 192
#define MLDW   36

__global__ __launch_bounds__(256, 4) void main_kernel(
    const float* __restrict__ text, const float* __restrict__ kw2t,
    const float* __restrict__ kw3v, const float* __restrict__ Q,
    float* __restrict__ out)
{
  __shared__ float sbuf[2][96 * MLDW];   // 2 x 13824 B = 27648 B

  const int tid = threadIdx.x;
  const int nl = tid >> 4;
  const int ml = tid & 15;
  const int n0 = blockIdx.y * 16;
  const int m0 = blockIdx.x * 64;
  const int z  = blockIdx.z;
  const int n  = n0 + nl;
  const int mA = m0 + ml, mB = mA + 16, mC = mA + 32, mD = mA + 48;
  const int dbase = z * DRANGE;

  float cA = 0.f, cB = 0.f, cC = 0.f, cD = 0.f;
  #pragma unroll
  for (int zz = 0; zz < 4; ++zz) {
    const float* q = Q + (size_t)zz * NN * MM + (size_t)n * MM;
    cA += q[mA]; cB += q[mB]; cC += q[mC]; cD += q[mD];
  }
  cA = fast_tanh(cA); cB = fast_tanh(cB);
  cC = fast_tanh(cC); cD = fast_tanh(cD);
  const f32x2 cA2 = {cA, cA}, cB2 = {cB, cB};
  const f32x2 cC2 = {cC, cC}, cD2 = {cD, cD};
  const f32x2 one2 = {1.0f, 1.0f};

  f32x2 aAL = {0.f, 0.f}, aAH = {0.f, 0.f};
  f32x2 aBL = {0.f, 0.f}, aBH = {0.f, 0.f};
  f32x2 aCL = {0.f, 0.f}, aCH = {0.f, 0.f};
  f32x2 aDL = {0.f, 0.f}, aDH = {0.f, 0.f};

  // staging: 96 rows (text 0..15 | kw2t 16..31 | kw3v 32..95) x 32 cols
  const int srow = tid >> 3;              // 0..31
  const int sc   = (tid & 7) << 2;        // 0,4,...,28
  const float* g1 = (srow < 16)
      ? &text[(size_t)(n0 + srow) * DD + dbase + sc]
      : &kw2t[(size_t)(n0 + srow - 16) * DD + dbase + sc];
  const float* g3a = &kw3v[(size_t)(m0 + srow) * DD + dbase + sc];
  const float* g3b = &kw3v[(size_t)(m0 + 32 + srow) * DD + dbase + sc];
  const int w1  = srow * MLDW + sc;          // rows 0..31 (text | kw2t)
  const int w3a = (32 + srow) * MLDW + sc;   // rows 32..63 (kw3v m 0..31)
  const int w3b = (64 + srow) * MLDW + sc;   // rows 64..95 (kw3v m 32..63)

  // prologue: stage chunk 0 into buffer 0
  float4 r1  = *(const float4*)g1;
  float4 r3a = *(const float4*)g3a;
  float4 r3b = *(const float4*)g3b;
  int p = 0;
  *(float4*)&sbuf[0][w1]  = r1;
  *(float4*)&sbuf[0][w3a] = r3a;
  *(float4*)&sbuf[0][w3b] = r3b;
  __syncthreads();

  #pragma unroll
  for (int c = 0; c < DRANGE / DCH; ++c) {   // 6 chunks
    const bool more = (c + 1 < DRANGE / DCH);
    if (more) {  // prefetch next chunk; compute below hides latency
      r1  = *(const float4*)(g1  + (c + 1) * DCH);
      r3a = *(const float4*)(g3a + (c + 1) * DCH);
      r3b = *(const float4*)(g3b + (c + 1) * DCH);
    }
    const float* bp = sbuf[p];
    #pragma unroll 4
    for (int j = 0; j < DCH; j += 4) {
      const float4 tv4 = *(const float4*)&bp[nl * MLDW + j];
      const float4 w24 = *(const float4*)&bp[(16 + nl) * MLDW + j];
      const float4 a34 = *(const float4*)&bp[(32 + ml) * MLDW + j];
      const float4 b34 = *(const float4*)&bp[(48 + ml) * MLDW + j];
      const float4 c34 = *(const float4*)&bp[(64 + ml) * MLDW + j];
      const float4 d34 = *(const float4*)&bp[(80 + ml) * MLDW + j];
      const f32x2 tvL = {tv4.x, tv4.y}, tvH = {tv4.z, tv4.w};
      const f32x2 w2L = {w24.x, w24.y}, w2H = {w24.z, w24.w};

      f32x2 gAL = (f32x2){a34.x, a34.y} * cA2 + w2L;   // v_pk_fma_f32
      f32x2 gAH = (f32x2){a34.z, a34.w} * cA2 + w2H;
      f32x2 gBL = (f32x2){b34.x, b34.y} * cB2 + w2L;
      f32x2 gBH = (f32x2){b34.z, b34.w} * cB2 + w2H;
      f32x2 gCL = (f32x2){c34.x, c34.y} * cC2 + w2L;
      f32x2 gCH = (f32x2){c34.z, c34.w} * cC2 + w2H;
      f32x2 gDL = (f32x2){d34.x, d34.y} * cD2 + w2L;
      f32x2 gDH = (f32x2){d34.z, d34.w} * cD2 + w2H;
      gAL.x = fexp(gAL.x); gAL.y = fexp(gAL.y);   // quarter-rate trans
      gAH.x = fexp(gAH.x); gAH.y = fexp(gAH.y);
      gBL.x = fexp(gBL.x); gBL.y = fexp(gBL.y);
      gBH.x = fexp(gBH.x); gBH.y = fexp(gBH.y);
      gCL.x = fexp(gCL.x); gCL.y = fexp(gCL.y);
      gCH.x = fexp(gCH.x); gCH.y = fexp(gCH.y);
      gDL.x = fexp(gDL.x); gDL.y = fexp(gDL.y);
      gDH.x = fexp(gDH.x); gDH.y = fexp(gDH.y);
      gAL = gAL + one2; gAH = gAH + one2;         // v_pk_add_f32
      gBL = gBL + one2; gBH = gBH + one2;
      gCL = gCL + one2; gCH = gCH + one2;
      gDL = gDL + one2; gDH = gDH + one2;
      gAL.x = frcp(gAL.x); gAL.y = frcp(gAL.y);
      gAH.x = frcp(gAH.x); gAH.y = frcp(gAH.y);
      gBL.x = frcp(gBL.x); gBL.y = frcp(gBL.y);
      gBH.x = frcp(gBH.x); gBH.y = frcp(gBH.y);
      gCL.x = frcp(gCL.x); gCL.y = frcp(gCL.y);
      gCH.x = frcp(gCH.x); gCH.y = frcp(gCH.y);
      gDL.x = frcp(gDL.x); gDL.y = frcp(gDL.y);
      gDH.x = frcp(gDH.x); gDH.y = frcp(gDH.y);
      aAL = tvL * gAL + aAL; aAH = tvH * gAH + aAH;   // v_pk_fma accumulate
      aBL = tvL * gBL + aBL; aBH = tvH * gBH + aBH;
      aCL = tvL * gCL + aCL; aCH = tvH * gCH + aCH;
      aDL = tvL * gDL + aDL; aDH = tvH * gDH + aDH;
    }
    if (more) {
      const int q = p ^ 1;
      *(float4*)&sbuf[q][w1]  = r1;
      *(float4*)&sbuf[q][w3a] = r3a;
      *(float4*)&sbuf[q][w3b] = r3b;
    }
    __syncthreads();   // single barrier per chunk
    p ^= 1;
  }

  float* op = out + (size_t)n * MM;
  unsafeAtomicAdd(&op[mA], -2.0f * ((aAL.x + aAL.y) + (aAH.x + aAH.y)));
  unsafeAtomicAdd(&op[mB], -2.0f * ((aBL.x + aBL.y) + (aBH.x + aBH.y)));
  unsafeAtomicAdd(&op[mC], -2.0f * ((aCL.x + aCL.y) + (aCH.x + aCH.y)));
  unsafeAtomicAdd(&op[mD], -2.0f * ((aDL.x + aDL.y) + (aDH.x + aDH.y)));
}

// ---- launcher --------------------------------------------------------------
extern "C" void kernel_launch(void* const* d_in, const int* in_sizes, int n_in,
                              void* d_out, int out_size, void* d_ws, size_t ws_size,
                              hipStream_t stream) {
  const float* text   = (const float*)d_in[0];
  const float* visual = (const float*)d_in[1];
  const float* W1     = (const float*)d_in[2];
  const float* W2     = (const float*)d_in[3];
  const float* W3     = (const float*)d_in[4];
  float* out = (float*)d_out;

  // Workspace byte layout (peak 14.25 MB, proven available):
  //   th/tl/vh/vl : f16 hi/lo of text, visual     (4 x 768 KB)
  //   w1t/w2t h,l : f16 hi/lo of W1^T,W2^T [j][k] (4 x 1.125 MB)
  //   w3 h/l      : f16 hi/lo of W3 [j][k]        (2 x 1.125 MB)
  //   Ah/Al       : f16 hi/lo of A                (2 x 768 KB)
  //   kw2t/kw3v   : fp32                          (2 x 1.5 MB)
  // Overlay (stream-serial; sources dead before overwrite):
  //   Q (4 MB) -> w1th..w2tl  (dead after mfma1; mfma2 writes Q)
  char* base = (char*)d_ws;
  ushort* th   = (ushort*)(base);
  ushort* tl   = (ushort*)(base + 786432);
  ushort* vh   = (ushort*)(base + 1572864);
  ushort* vl   = (ushort*)(base + 2359296);
  ushort* w1th = (ushort*)(base + 3145728);
  ushort* w1tl = (ushort*)(base + 4325376);
  ushort* w2th = (ushort*)(base + 5505024);
  ushort* w2tl = (ushort*)(base + 6684672);
  ushort* w3h  = (ushort*)(base + 7864320);
  ushort* w3l  = (ushort*)(base + 9043968);
  ushort* Ah   = (ushort*)(base + 10223616);
  ushort* Al   = (ushort*)(base + 11010048);
  float*  kw2t = (float*) (base + 11796480);
  float*  kw3v = (float*) (base + 13369344);
  float*  Q    = (float*) (base + 3145728);   // 4 MB over w1t/w2t

  hipLaunchKernelGGL(prep_kernel, dim3(2752), dim3(256), 0, stream,
                     text, visual, W1, W2, W3,
                     th, tl, vh, vl, w3h, w3l, w1th, w1tl, w2th, w2tl, out);
  hipLaunchKernelGGL(mfma1_kernel, dim3(DD / 64, NN / 32, 3), dim3(256), 0, stream,
                     th, tl, vh, vl, w1th, w1tl, w2th, w2tl, w3h, w3l,
                     Ah, Al, kw2t, kw3v);
  hipLaunchKernelGGL(mfma2_kernel, dim3(MM / 64, NN / 32, 4), dim3(256), 0, stream,
                     Ah, Al, vh, vl, Q);
  hipLaunchKernelGGL(main_kernel, dim3(MM / 64, NN / 16, 4), dim3(256), 0, stream,
                     text, kw2t, kw3v, Q, out);
}

// Round 14
// 127.123 us; speedup vs baseline: 1.0204x; 1.0204x over previous
//
#include <hip/hip_runtime.h>

// Problem dims (hard-coded in reference)
#define DD   768
#define NN   512
#define MM   512

#define PRE_K 2.88539008177792681472f   // 2*log2(e)

typedef _Float16 h8 __attribute__((ext_vector_type(8)));  // 8 f16 (4 VGPRs)
typedef __attribute__((ext_vector_type(4))) float f32x4;  // MFMA C/D
typedef __attribute__((ext_vector_type(2))) float f32x2;  // packed fp32 (v_pk_*)

__device__ __forceinline__ float fexp(float x) { return __builtin_amdgcn_exp2f(x); }
__device__ __forceinline__ float frcp(float x) { return __builtin_amdgcn_rcpf(x); }
// tanh(x) = 1 - 2/(1 + e^{2x}); saturates correctly via exp2->inf/0 + rcp.
__device__ __forceinline__ float fast_tanh(float x) {
  return 1.0f - 2.0f * frcp(fexp(PRE_K * x) + 1.0f);
}
// FINAL LEDGER (R14 = R12 revert, BEST 127.5us):
//   main: 43.2us = ~2x the 20.5us trans-pipe floor. Pinned by: occupancy
//     26-40% (R6/R12/R13), LDS-issue density 2.7x (R13), full-rate issue
//     halved (R12 pk-math, the one win: -1.6us) -> all configs land 43-45.
//   support+gaps ~41us: six structural rewrites flat/negative (BK64 R7,
//     in-GEMM convert R8, prep-delete R8, associativity V1t R10/R11,
//     z-fusion R1/R3, mega-kernel R17).
//   harness re-poison fill ~42us (measured R9): in-stream, not controllable.
// Falsified: Schraudolph exp2 (R13-orig), Q-fusion at low occupancy (R1),
//   LDS-diet via global broadcast reads (R3), launch_bounds(256,8) VGPR
//   squeeze -> scratch spills (R5), BK64 (R7), 16x64 tile (R13).

// fp32 -> f16 hi/lo split (pair covers ~21 mantissa bits)
__device__ __forceinline__ void splitf(float x, ushort& h, ushort& l) {
  const _Float16 hh = (_Float16)x;
  const _Float16 ll = (_Float16)(x - (float)hh);
  h = __builtin_bit_cast(unsigned short, hh);
  l = __builtin_bit_cast(unsigned short, ll);
}

// ---- fused prep (R0 verbatim) ----------------------------------------------
// blocks [0,1344): elementwise f16 hi/lo split of text/visual/W3
// blocks [1344,2496): transpose+split W1/W2 -> [j][k]
// blocks [2496,2752): T-init — out[n,m] = T[n] = sum_d text[n,d]
__global__ __launch_bounds__(256) void prep_kernel(
    const float* __restrict__ text, const float* __restrict__ visual,
    const float* __restrict__ W1, const float* __restrict__ W2,
    const float* __restrict__ W3,
    ushort* __restrict__ th, ushort* __restrict__ tl,
    ushort* __restrict__ vh, ushort* __restrict__ vl,
    ushort* __restrict__ w3h, ushort* __restrict__ w3l,
    ushort* __restrict__ w1th, ushort* __restrict__ w1tl,
    ushort* __restrict__ w2th, ushort* __restrict__ w2tl,
    float* __restrict__ out)
{
  __shared__ float Lt[32][33];
  const int b = blockIdx.x;
  const int t = threadIdx.x;

  if (b < 1344) {
    const float* src; ushort *dh, *dl; size_t off;
    if (b < 384)      { src = text;   dh = th;  dl = tl;  off = (size_t)b * 1024; }
    else if (b < 768) { src = visual; dh = vh;  dl = vl;  off = (size_t)(b - 384) * 1024; }
    else              { src = W3;     dh = w3h; dl = w3l; off = (size_t)(b - 768) * 1024; }
    const size_t i = off + (size_t)t * 4;
    const float4 v = *(const float4*)&src[i];
    ushort4 h, l;
    splitf(v.x, h.x, l.x); splitf(v.y, h.y, l.y);
    splitf(v.z, h.z, l.z); splitf(v.w, h.w, l.w);
    *(ushort4*)&dh[i] = h;
    *(ushort4*)&dl[i] = l;
  } else if (b < 2496) {
    const int tt = b - 1344;
    const bool second = tt >= 576;
    const int tile = second ? tt - 576 : tt;
    const float* W = second ? W2 : W1;
    ushort* oh = second ? w2th : w1th;
    ushort* ol = second ? w2tl : w1tl;
    const int k0 = (tile / 24) * 32, j0 = (tile % 24) * 32;
    {
      const int k = t >> 3, j4 = (t & 7) * 4;
      const float4 v = *(const float4*)&W[(size_t)(k0 + k) * DD + j0 + j4];
      Lt[j4 + 0][k] = v.x; Lt[j4 + 1][k] = v.y;
      Lt[j4 + 2][k] = v.z; Lt[j4 + 3][k] = v.w;
    }
    __syncthreads();
    {
      const int j = t >> 3, k4 = (t & 7) * 4;
      ushort4 h, l;
      splitf(Lt[j][k4 + 0], h.x, l.x); splitf(Lt[j][k4 + 1], h.y, l.y);
      splitf(Lt[j][k4 + 2], h.z, l.z); splitf(Lt[j][k4 + 3], h.w, l.w);
      *(ushort4*)&oh[(size_t)(j0 + j) * DD + k0 + k4] = h;
      *(ushort4*)&ol[(size_t)(j0 + j) * DD + k0 + k4] = l;
    }
  } else {
    // T-init: rows n0, n0+1; out[row][:] = T[row]
    float* red = (float*)Lt;          // 258 floats needed, 1056 available
    const int u = b - 2496;
    const int n0 = u * 2;
    const int half = t >> 7;
    const int lt = t & 127;

    const float* tr = text + (size_t)(n0 + half) * DD;
    float s = 0.f;
    #pragma unroll
    for (int i = 0; i < DD / 128; ++i) s += tr[lt + i * 128];
    red[t] = s;
    __syncthreads();
    #pragma unroll
    for (int st = 64; st > 0; st >>= 1) {
      if (lt < st) red[t] += red[t + st];
      __syncthreads();
    }
    const float Tn = red[half << 7];
    float4 o; o.x = Tn; o.y = Tn; o.z = Tn; o.w = Tn;
    *(float4*)&out[(size_t)(n0 + half) * MM + lt * 4] = o;
  }
}

// ---- staged-LDS MFMA GEMM core, 32x64 tile + k0 (R6-proven) ----------------
#define BK   32
#define LROW 40            // padded LDS row stride (f16): 2-way banks, 16B-aligned
#define APL  (32 * LROW)   // one A plane (rows x LROW), in ushorts
#define BPL  (64 * LROW)   // one B plane

template <bool ALO>
__device__ __forceinline__ void gemm_core32(
    ushort* __restrict__ As, ushort* __restrict__ Bs,  // [2 buf][2 hi/lo][plane]
    const ushort* __restrict__ Ahg, const ushort* __restrict__ Alg,
    const ushort* __restrict__ Bhg, const ushort* __restrict__ Blg,
    int i0, int j0, int k0, int nsteps, f32x4* acc)
{
  const int tid = threadIdx.x;
  const int row = tid >> 2;             // 0..63 staging row (B); 0..31 for A
  const int ks8 = (tid & 3) * 8;        // 0,8,16,24 (f16)
  const bool doA = (row < 32);          // waves 0,1 stage A too (wave-uniform)
  const size_t ga = (size_t)(i0 + row) * DD + k0 + ks8;
  const size_t gb = (size_t)(j0 + row) * DD + k0 + ks8;
  const int lw = row * LROW + ks8;

  const int lane = tid & 63, wave = tid >> 6;
  const int r15 = lane & 15, quad = lane >> 4;
  const int wr = wave >> 1, wc = wave & 1;              // 2x2 wave grid
  const int fa = (wr * 16 + r15) * LROW + quad * 8;     // A frag offset
  const int fb = (wc * 32 + r15) * LROW + quad * 8;     // B frag base

  h8 pah, pal, pbh, pbl;
  if (doA) {
    pah = *(const h8*)(Ahg + ga);
    if (ALO) pal = *(const h8*)(Alg + ga);
  }
  pbh = *(const h8*)(Bhg + gb);
  pbl = *(const h8*)(Blg + gb);

  int p = 0;
  if (doA) {
    *(h8*)&As[lw] = pah;
    if (ALO) *(h8*)&As[APL + lw] = pal;
  }
  *(h8*)&Bs[lw] = pbh;
  *(h8*)&Bs[BPL + lw] = pbl;
  __syncthreads();

  for (int s = 0; s < nsteps; ++s) {
    const bool more = (s + 1 < nsteps);
    if (more) {  // issue next chunk's globals; MFMA below hides latency
      if (doA) {
        pah = *(const h8*)(Ahg + ga + (s + 1) * BK);
        if (ALO) pal = *(const h8*)(Alg + ga + (s + 1) * BK);
      }
      pbh = *(const h8*)(Bhg + gb + (s + 1) * BK);
      pbl = *(const h8*)(Blg + gb + (s + 1) * BK);
    }
    ushort* Ac = As + p * 2 * APL;
    ushort* Bc = Bs + p * 2 * BPL;
    const h8 a_h = *(const h8*)&Ac[fa];
    h8 a_l; if (ALO) a_l = *(const h8*)&Ac[APL + fa];
    h8 b_h[2], b_l[2];
    #pragma unroll
    for (int c = 0; c < 2; ++c) {
      b_h[c] = *(const h8*)&Bc[fb + c * 16 * LROW];
      b_l[c] = *(const h8*)&Bc[BPL + fb + c * 16 * LROW];
    }
    #pragma unroll
    for (int c = 0; c < 2; ++c)
      acc[c] = __builtin_amdgcn_mfma_f32_16x16x32_f16(a_h, b_h[c], acc[c], 0, 0, 0);
    #pragma unroll
    for (int c = 0; c < 2; ++c)
      acc[c] = __builtin_amdgcn_mfma_f32_16x16x32_f16(a_h, b_l[c], acc[c], 0, 0, 0);
    if (ALO) {
      #pragma unroll
      for (int c = 0; c < 2; ++c)
        acc[c] = __builtin_amdgcn_mfma_f32_16x16x32_f16(a_l, b_h[c], acc[c], 0, 0, 0);
    }
    if (more) {
      const int q = p ^ 1;
      ushort* An = As + q * 2 * APL;
      ushort* Bn = Bs + q * 2 * BPL;
      if (doA) {
        *(h8*)&An[lw] = pah;
        if (ALO) *(h8*)&An[APL + lw] = pal;
      }
      *(h8*)&Bn[lw] = pbh;
      *(h8*)&Bn[BPL + lw] = pbl;
    }
    __syncthreads();
    p ^= 1;
  }
}

// z=0: A=text@W1 -> Ah/Al(f16)  z=1: kw2t=PRE_K*text@W2  z=2: kw3v=PRE_K*visual@W3^T
// grid (DD/64, NN/32, 3) = (12, 16, 3) = 576 blocks.
__global__ __launch_bounds__(256) void mfma1_kernel(
    const ushort* __restrict__ th, const ushort* __restrict__ tl,
    const ushort* __restrict__ vh, const ushort* __restrict__ vl,
    const ushort* __restrict__ w1th, const ushort* __restrict__ w1tl,
    const ushort* __restrict__ w2th, const ushort* __restrict__ w2tl,
    const ushort* __restrict__ w3h, const ushort* __restrict__ w3l,
    ushort* __restrict__ Ah, ushort* __restrict__ Al,
    float* __restrict__ kw2t, float* __restrict__ kw3v)
{
  __shared__ ushort As[2 * 2 * APL];   // 10240 B
  __shared__ ushort Bs[2 * 2 * BPL];   // 20480 B

  const int z  = blockIdx.z;
  const int j0 = blockIdx.x * 64;
  const int i0 = blockIdx.y * 32;

  f32x4 acc[2];
  acc[0] = (f32x4){0.f, 0.f, 0.f, 0.f};
  acc[1] = (f32x4){0.f, 0.f, 0.f, 0.f};

  if (z == 0)
    gemm_core32<true >(As, Bs, th, tl, w1th, w1tl, i0, j0, 0, DD / BK, acc);
  else if (z == 1)
    gemm_core32<false>(As, Bs, th, tl, w2th, w2tl, i0, j0, 0, DD / BK, acc);
  else
    gemm_core32<false>(As, Bs, vh, vl, w3h,  w3l,  i0, j0, 0, DD / BK, acc);

  const int lane = threadIdx.x & 63, wave = threadIdx.x >> 6;
  const int r15 = lane & 15, quad = lane >> 4;
  const int wr = wave >> 1, wc = wave & 1;
  // C/D layout: col=lane&15 (B row j), row=quad*4+reg (A row i)
  if (z == 0) {
    #pragma unroll
    for (int c = 0; c < 2; ++c)
      #pragma unroll
      for (int r = 0; r < 4; ++r) {
        const size_t o = (size_t)(i0 + wr * 16 + quad * 4 + r) * DD
                       + j0 + wc * 32 + c * 16 + r15;
        splitf(acc[c][r], Ah[o], Al[o]);
      }
  } else {
    float* Out = (z == 1) ? kw2t : kw3v;
    #pragma unroll
    for (int c = 0; c < 2; ++c)
      #pragma unroll
      for (int r = 0; r < 4; ++r)
        Out[(size_t)(i0 + wr * 16 + quad * 4 + r) * DD + j0 + wc * 32 + c * 16 + r15] =
            acc[c][r] * PRE_K;
  }
}

// Q[z] = A @ visual^T over K quarter z.  grid (8, 16, 4) = 512 blocks (2/CU).
__global__ __launch_bounds__(256) void mfma2_kernel(
    const ushort* __restrict__ Ah, const ushort* __restrict__ Al,
    const ushort* __restrict__ vh, const ushort* __restrict__ vl,
    float* __restrict__ Q)
{
  __shared__ ushort As[2 * 2 * APL];
  __shared__ ushort Bs[2 * 2 * BPL];

  const int z  = blockIdx.z;
  const int j0 = blockIdx.x * 64;
  const int i0 = blockIdx.y * 32;

  f32x4 acc[2];
  acc[0] = (f32x4){0.f, 0.f, 0.f, 0.f};
  acc[1] = (f32x4){0.f, 0.f, 0.f, 0.f};
  gemm_core32<true>(As, Bs, Ah, Al, vh, vl, i0, j0, z * (DD / 4), (DD / 4) / BK, acc);

  const int lane = threadIdx.x & 63, wave = threadIdx.x >> 6;
  const int r15 = lane & 15, quad = lane >> 4;
  const int wr = wave >> 1, wc = wave & 1;
  float* Qp = Q + (size_t)z * NN * MM;
  #pragma unroll
  for (int c = 0; c < 2; ++c)
    #pragma unroll
    for (int r = 0; r < 4; ++r)
      Qp[(size_t)(i0 + wr * 16 + quad * 4 + r) * MM + j0 + wc * 32 + c * 16 + r15] =
          acc[c][r];
}

// ---- main fused kernel (R12-proven: R6 structure + packed f32x2 math) ------
// Per j-group: 24 full-rate scalar slots -> 12 v_pk slots (arg fma, +1 add,
// acc fma packed); 16 trans (exp/rcp) unchanged. Accumulator slot order
// preserved (aAL/aAH = old aA.xy/zw), so reductions are bit-identical.
#define DCH    32
#define DRANGE 192
#define MLDW   36

__global__ __launch_bounds__(256, 4) void main_kernel(
    const float* __restrict__ text, const float* __restrict__ kw2t,
    const float* __restrict__ kw3v, const float* __restrict__ Q,
    float* __restrict__ out)
{
  __shared__ float sbuf[2][64 * MLDW];   // 2 x 9216 B = 18432 B

  const int tid = threadIdx.x;
  const int nl = tid >> 4;
  const int ml = tid & 15;
  const int n0 = blockIdx.y * 16;
  const int m0 = blockIdx.x * 32;
  const int z  = blockIdx.z;
  const int n  = n0 + nl;
  const int mA = m0 + ml, mB = mA + 16;
  const int dbase = z * DRANGE;

  float cA = 0.f, cB = 0.f;
  #pragma unroll
  for (int zz = 0; zz < 4; ++zz) {
    const float* q = Q + (size_t)zz * NN * MM + (size_t)n * MM;
    cA += q[mA]; cB += q[mB];
  }
  cA = fast_tanh(cA); cB = fast_tanh(cB);
  const f32x2 cA2 = {cA, cA}, cB2 = {cB, cB};
  const f32x2 one2 = {1.0f, 1.0f};

  f32x2 aAL = {0.f, 0.f}, aAH = {0.f, 0.f};
  f32x2 aBL = {0.f, 0.f}, aBH = {0.f, 0.f};

  // staging: 64 rows (text 0..15 | kw2t 16..31 | kw3v 32..63) x 32 cols
  const int srow = tid >> 3;              // 0..31
  const int sc   = (tid & 7) << 2;        // 0,4,...,28
  const float* g1 = (srow < 16)
      ? &text[(size_t)(n0 + srow) * DD + dbase + sc]
      : &kw2t[(size_t)(n0 + srow - 16) * DD + dbase + sc];
  const float* g3 = &kw3v[(size_t)(m0 + srow) * DD + dbase + sc];
  const int w1 = srow * MLDW + sc;          // rows 0..31 (text | kw2t)
  const int w3 = (32 + srow) * MLDW + sc;   // rows 32..63 (kw3v, 32 rows)

  // prologue: stage chunk 0 into buffer 0
  float4 r1 = *(const float4*)g1;
  float4 r3 = *(const float4*)g3;
  int p = 0;
  *(float4*)&sbuf[0][w1] = r1;
  *(float4*)&sbuf[0][w3] = r3;
  __syncthreads();

  #pragma unroll
  for (int c = 0; c < DRANGE / DCH; ++c) {   // 6 chunks
    const bool more = (c + 1 < DRANGE / DCH);
    if (more) {  // prefetch next chunk; compute below hides latency
      r1 = *(const float4*)(g1 + (c + 1) * DCH);
      r3 = *(const float4*)(g3 + (c + 1) * DCH);
    }
    const float* bp = sbuf[p];
    #pragma unroll 4
    for (int j = 0; j < DCH; j += 4) {
      const f32x2 tvL  = *(const f32x2*)&bp[nl * MLDW + j];
      const f32x2 tvH  = *(const f32x2*)&bp[nl * MLDW + j + 2];
      const f32x2 w2L  = *(const f32x2*)&bp[(16 + nl) * MLDW + j];
      const f32x2 w2H  = *(const f32x2*)&bp[(16 + nl) * MLDW + j + 2];
      const f32x2 a3L  = *(const f32x2*)&bp[(32 + ml) * MLDW + j];
      const f32x2 a3H  = *(const f32x2*)&bp[(32 + ml) * MLDW + j + 2];
      const f32x2 b3L  = *(const f32x2*)&bp[(48 + ml) * MLDW + j];
      const f32x2 b3H  = *(const f32x2*)&bp[(48 + ml) * MLDW + j + 2];

      f32x2 gAL = a3L * cA2 + w2L;    // v_pk_fma_f32
      f32x2 gAH = a3H * cA2 + w2H;
      f32x2 gBL = b3L * cB2 + w2L;
      f32x2 gBH = b3H * cB2 + w2H;
      gAL.x = fexp(gAL.x); gAL.y = fexp(gAL.y);   // quarter-rate trans (scalar)
      gAH.x = fexp(gAH.x); gAH.y = fexp(gAH.y);
      gBL.x = fexp(gBL.x); gBL.y = fexp(gBL.y);
      gBH.x = fexp(gBH.x); gBH.y = fexp(gBH.y);
      gAL = gAL + one2;               // v_pk_add_f32
      gAH = gAH + one2;
      gBL = gBL + one2;
      gBH = gBH + one2;
      gAL.x = frcp(gAL.x); gAL.y = frcp(gAL.y);
      gAH.x = frcp(gAH.x); gAH.y = frcp(gAH.y);
      gBL.x = frcp(gBL.x); gBL.y = frcp(gBL.y);
      gBH.x = frcp(gBH.x); gBH.y = frcp(gBH.y);
      aAL = tvL * gAL + aAL;          // v_pk_fma_f32 accumulate
      aAH = tvH * gAH + aAH;
      aBL = tvL * gBL + aBL;
      aBH = tvH * gBH + aBH;
    }
    if (more) {
      const int q = p ^ 1;
      *(float4*)&sbuf[q][w1] = r1;
      *(float4*)&sbuf[q][w3] = r3;
    }
    __syncthreads();   // single barrier per chunk
    p ^= 1;
  }

  float* op = out + (size_t)n * MM;
  unsafeAtomicAdd(&op[mA], -2.0f * ((aAL.x + aAL.y) + (aAH.x + aAH.y)));
  unsafeAtomicAdd(&op[mB], -2.0f * ((aBL.x + aBL.y) + (aBH.x + aBH.y)));
}

// ---- launcher --------------------------------------------------------------
extern "C" void kernel_launch(void* const* d_in, const int* in_sizes, int n_in,
                              void* d_out, int out_size, void* d_ws, size_t ws_size,
                              hipStream_t stream) {
  const float* text   = (const float*)d_in[0];
  const float* visual = (const float*)d_in[1];
  const float* W1     = (const float*)d_in[2];
  const float* W2     = (const float*)d_in[3];
  const float* W3     = (const float*)d_in[4];
  float* out = (float*)d_out;

  // Workspace byte layout (peak 14.25 MB, proven available):
  //   th/tl/vh/vl : f16 hi/lo of text, visual     (4 x 768 KB)
  //   w1t/w2t h,l : f16 hi/lo of W1^T,W2^T [j][k] (4 x 1.125 MB)
  //   w3 h/l      : f16 hi/lo of W3 [j][k]        (2 x 1.125 MB)
  //   Ah/Al       : f16 hi/lo of A                (2 x 768 KB)
  //   kw2t/kw3v   : fp32                          (2 x 1.5 MB)
  // Overlay (stream-serial; sources dead before overwrite):
  //   Q (4 MB) -> w1th..w2tl  (dead after mfma1; mfma2 writes Q)
  char* base = (char*)d_ws;
  ushort* th   = (ushort*)(base);
  ushort* tl   = (ushort*)(base + 786432);
  ushort* vh   = (ushort*)(base + 1572864);
  ushort* vl   = (ushort*)(base + 2359296);
  ushort* w1th = (ushort*)(base + 3145728);
  ushort* w1tl = (ushort*)(base + 4325376);
  ushort* w2th = (ushort*)(base + 5505024);
  ushort* w2tl = (ushort*)(base + 6684672);
  ushort* w3h  = (ushort*)(base + 7864320);
  ushort* w3l  = (ushort*)(base + 9043968);
  ushort* Ah   = (ushort*)(base + 10223616);
  ushort* Al   = (ushort*)(base + 11010048);
  float*  kw2t = (float*) (base + 11796480);
  float*  kw3v = (float*) (base + 13369344);
  float*  Q    = (float*) (base + 3145728);   // 4 MB over w1t/w2t

  hipLaunchKernelGGL(prep_kernel, dim3(2752), dim3(256), 0, stream,
                     text, visual, W1, W2, W3,
                     th, tl, vh, vl, w3h, w3l, w1th, w1tl, w2th, w2tl, out);
  hipLaunchKernelGGL(mfma1_kernel, dim3(DD / 64, NN / 32, 3), dim3(256), 0, stream,
                     th, tl, vh, vl, w1th, w1tl, w2th, w2tl, w3h, w3l,
                     Ah, Al, kw2t, kw3v);
  hipLaunchKernelGGL(mfma2_kernel, dim3(MM / 64, NN / 32, 4), dim3(256), 0, stream,
                     Ah, Al, vh, vl, Q);
  hipLaunchKernelGGL(main_kernel, dim3(MM / 32, NN / 16, 4), dim3(256), 0, stream,
                     text, kw2t, kw3v, Q, out);
}